// Round 3
// baseline (82.092 us; speedup 1.0000x reference)
//
#include <hip/hip_runtime.h>
#include <math.h>

#define LOG2E 1.4426950408889634f
#define LN2   0.6931471805599453f

static constexpr int M = 1024;
static constexpr int N = 65536;

// ws layout: float coef[M*8] (c0..c5,pad,pad per component, all pre-scaled by
// LOG2E; c0 also has the global shift L folded in), then ws[M*8] = LOG2E*L.

__device__ inline float wave_max64(float v) {
    #pragma unroll
    for (int o = 32; o > 0; o >>= 1) v = fmaxf(v, __shfl_xor(v, o));
    return v;
}
__device__ inline float wave_sum64(float v) {
    #pragma unroll
    for (int o = 32; o > 0; o >>= 1) v += __shfl_xor(v, o);
    return v;
}

__global__ __launch_bounds__(1024)
void gm_prep(const float* __restrict__ mu,
             const float* __restrict__ A,
             const float* __restrict__ w,
             float* __restrict__ ws) {
    __shared__ float r[16];
    const int j    = threadIdx.x;
    const int lane = j & 63;
    const int wv   = j >> 6;

    // gamma = A A^T (symmetric 2x2)
    const float4 a = ((const float4*)A)[j];          // a00,a01,a10,a11
    const float g00 = a.x*a.x + a.y*a.y;
    const float g01 = a.x*a.z + a.y*a.w;
    const float g11 = a.z*a.z + a.w*a.w;
    const float2 m  = ((const float2*)mu)[j];
    const float gm0 = g00*m.x + g01*m.y;
    const float gm1 = g01*m.x + g11*m.y;
    const float mGm = gm0*m.x + gm1*m.y;
    const float det = g00*g11 - g01*g01;
    const float wj  = w[j];

    // block max of w
    float t = wave_max64(wj);
    if (lane == 0) r[wv] = t;
    __syncthreads();
    float wmax = r[0];
    #pragma unroll
    for (int i = 1; i < 16; i++) wmax = fmaxf(wmax, r[i]);
    __syncthreads();

    // block sum of exp(w - wmax)
    t = wave_sum64(expf(wj - wmax));
    if (lane == 0) r[wv] = t;
    __syncthreads();
    float se = 0.0f;
    #pragma unroll
    for (int i = 0; i < 16; i++) se += r[i];
    const float lse = wmax + logf(se);
    __syncthreads();

    const float log_w = wj - lse + 0.5f * logf(det);

    // block max of log_w (global shift L; v = log_w - q <= L since q >= 0)
    t = wave_max64(log_w);
    if (lane == 0) r[wv] = t;
    __syncthreads();
    float L = r[0];
    #pragma unroll
    for (int i = 1; i < 16; i++) L = fmaxf(L, r[i]);

    float* c = ws + j*8;
    c[0] = LOG2E * (log_w - mGm - L);
    c[1] = LOG2E * 2.0f * gm0;
    c[2] = LOG2E * 2.0f * gm1;
    c[3] = -LOG2E * g00;
    c[4] = -LOG2E * 2.0f * g01;
    c[5] = -LOG2E * g11;
    c[6] = 0.0f;
    c[7] = 0.0f;
    if (j == 0) ws[M*8] = LOG2E * L;
}

// 1024 blocks x 512 threads (8 waves). Block = 64 samples (one per lane);
// the 8 waves split M 8-way (128 components each). Coefficient reads are
// wave-uniform -> scalar s_load into SGPRs: the hot loop has ZERO LDS ops
// and zero per-lane VMEM. 2048 threads/CU = 8 waves/SIMD.
__global__ __launch_bounds__(512)
void gm_main(const float* __restrict__ sample,
             const float* __restrict__ ws,
             float* __restrict__ out) {
    __shared__ float partial[8*64];
    const int t    = threadIdx.x;
    const int lane = t & 63;
    const int wv   = __builtin_amdgcn_readfirstlane(t >> 6);   // 0..7, SGPR

    const int i = blockIdx.x*64 + lane;
    const float2 p = ((const float2*)sample)[i];
    const float x0 = p.x, x1 = p.y;
    const float xx = x0*x0, xy = x0*x1, yy = x1*x1;

    // wave-uniform coefficient pointer -> SMEM scalar loads
    const float* __restrict__ c = ws + (size_t)wv * 128 * 8;

    float a0 = 0.0f, a1 = 0.0f, a2 = 0.0f, a3 = 0.0f;
    #pragma unroll 4
    for (int jj = 0; jj < 128; jj += 4) {
        const float* ca = c + (jj+0)*8;
        const float* cb = c + (jj+1)*8;
        const float* cc = c + (jj+2)*8;
        const float* cd = c + (jj+3)*8;
        // mul + 4 fma + add: every vector op reads at most 1 SGPR
        const float va = fmaf(ca[5], yy, fmaf(ca[4], xy, fmaf(ca[3], xx,
                         fmaf(ca[2], x1, ca[1]*x0)))) + ca[0];
        const float vb = fmaf(cb[5], yy, fmaf(cb[4], xy, fmaf(cb[3], xx,
                         fmaf(cb[2], x1, cb[1]*x0)))) + cb[0];
        const float vc = fmaf(cc[5], yy, fmaf(cc[4], xy, fmaf(cc[3], xx,
                         fmaf(cc[2], x1, cc[1]*x0)))) + cc[0];
        const float vd = fmaf(cd[5], yy, fmaf(cd[4], xy, fmaf(cd[3], xx,
                         fmaf(cd[2], x1, cd[1]*x0)))) + cd[0];
        a0 += __builtin_amdgcn_exp2f(va);
        a1 += __builtin_amdgcn_exp2f(vb);
        a2 += __builtin_amdgcn_exp2f(vc);
        a3 += __builtin_amdgcn_exp2f(vd);
    }
    partial[wv*64 + lane] = (a0 + a1) + (a2 + a3);
    __syncthreads();

    if (t < 64) {
        float s = 0.0f;
        #pragma unroll
        for (int w2 = 0; w2 < 8; w2++) s += partial[w2*64 + t];
        out[blockIdx.x*64 + t] = LN2 * (ws[M*8] + __builtin_amdgcn_logf(s));
    }
}

// Fallback if ws is too small (not expected; ws is ~256 MB).
__global__ __launch_bounds__(256)
void gm_fused(const float* __restrict__ sample,
              const float* __restrict__ mu,
              const float* __restrict__ A,
              const float* __restrict__ w,
              float* __restrict__ out) {
    __shared__ __align__(16) float coef[M*8];
    __shared__ float red[256];
    const int t = threadIdx.x;

    float wv[4], c0t[4], c1t[4], c2t[4], c3t[4], c4t[4], c5t[4];
    float wmaxl = -3.4e38f;
    #pragma unroll
    for (int k = 0; k < 4; k++) { wv[k] = w[t + 256*k]; wmaxl = fmaxf(wmaxl, wv[k]); }
    red[t] = wmaxl; __syncthreads();
    for (int off = 128; off > 0; off >>= 1) {
        if (t < off) red[t] = fmaxf(red[t], red[t+off]);
        __syncthreads();
    }
    const float wmax = red[0]; __syncthreads();
    float se = 0.0f;
    #pragma unroll
    for (int k = 0; k < 4; k++) se += expf(wv[k] - wmax);
    red[t] = se; __syncthreads();
    for (int off = 128; off > 0; off >>= 1) {
        if (t < off) red[t] = red[t] + red[t+off];
        __syncthreads();
    }
    const float lse = wmax + logf(red[0]); __syncthreads();

    float Lml = -3.4e38f;
    #pragma unroll
    for (int k = 0; k < 4; k++) {
        const int j = t + 256*k;
        const float4 a = ((const float4*)A)[j];
        const float g00 = a.x*a.x + a.y*a.y;
        const float g01 = a.x*a.z + a.y*a.w;
        const float g11 = a.z*a.z + a.w*a.w;
        const float2 m  = ((const float2*)mu)[j];
        const float gm0 = g00*m.x + g01*m.y;
        const float gm1 = g01*m.x + g11*m.y;
        const float mGm = gm0*m.x + gm1*m.y;
        const float det = g00*g11 - g01*g01;
        const float lw  = wv[k] - lse + 0.5f*logf(det);
        Lml = fmaxf(Lml, lw);
        c0t[k] = lw - mGm; c1t[k] = 2.0f*gm0; c2t[k] = 2.0f*gm1;
        c3t[k] = -g00; c4t[k] = -2.0f*g01; c5t[k] = -g11;
    }
    red[t] = Lml; __syncthreads();
    for (int off = 128; off > 0; off >>= 1) {
        if (t < off) red[t] = fmaxf(red[t], red[t+off]);
        __syncthreads();
    }
    const float L = red[0];
    #pragma unroll
    for (int k = 0; k < 4; k++) {
        float* c = coef + (t + 256*k)*8;
        c[0] = LOG2E*(c0t[k] - L); c[1] = LOG2E*c1t[k]; c[2] = LOG2E*c2t[k];
        c[3] = LOG2E*c3t[k]; c[4] = LOG2E*c4t[k]; c[5] = LOG2E*c5t[k];
    }
    __syncthreads();

    const int i = blockIdx.x*256 + t;
    const float2 xyv = ((const float2*)sample)[i];
    const float x0 = xyv.x, x1 = xyv.y;
    const float xx = x0*x0, xyp = x0*x1, yy = x1*x1;
    float s0 = 0.0f, s1 = 0.0f;
    #pragma unroll 8
    for (int jj = 0; jj < M; jj++) {
        const float* cc = coef + jj*8;
        const float v = fmaf(cc[5], yy, fmaf(cc[4], xyp, fmaf(cc[3], xx,
                        fmaf(cc[2], x1, fmaf(cc[1], x0, cc[0])))));
        const float e = __builtin_amdgcn_exp2f(v);
        if (jj & 1) s1 += e; else s0 += e;
    }
    out[i] = LN2 * (LOG2E*L + __builtin_amdgcn_logf(s0 + s1));
}

extern "C" void kernel_launch(void* const* d_in, const int* in_sizes, int n_in,
                              void* d_out, int out_size, void* d_ws, size_t ws_size,
                              hipStream_t stream) {
    const float* sample = (const float*)d_in[0];
    const float* mu     = (const float*)d_in[1];
    const float* A      = (const float*)d_in[2];
    const float* w      = (const float*)d_in[3];
    float* out = (float*)d_out;

    if (ws_size >= (size_t)(M*8 + 1) * sizeof(float)) {
        gm_prep<<<1, 1024, 0, stream>>>(mu, A, w, (float*)d_ws);
        gm_main<<<N/64, 512, 0, stream>>>(sample, (const float*)d_ws, out);
    } else {
        gm_fused<<<N/256, 256, 0, stream>>>(sample, mu, A, w, out);
    }
}

// Round 4
// 74.435 us; speedup vs baseline: 1.1029x; 1.1029x over previous
//
#include <hip/hip_runtime.h>
#include <math.h>

#define LOG2E 1.4426950408889634f
#define LN2   0.6931471805599453f

static constexpr int M = 1024;
static constexpr int N = 65536;

__device__ inline float wave_max64(float v) {
    #pragma unroll
    for (int o = 32; o > 0; o >>= 1) v = fmaxf(v, __shfl_xor(v, o));
    return v;
}
__device__ inline float wave_sum64(float v) {
    #pragma unroll
    for (int o = 32; o > 0; o >>= 1) v += __shfl_xor(v, o);
    return v;
}

// Single fused kernel: 256 blocks x 1024 threads (16 waves), 1 block/CU.
// Phase 1 (prep, redundant per block): thread j computes component j's
//   quadratic-form coefficients + block-wide log_softmax / shift reductions.
//   Coefficients packed stride-6 into LDS (24 KB).
// Phase 2 (main): block covers 256 samples; each of the 16 waves handles 64
//   components for ALL 256 samples (S=4 samples/lane). Component PAIRS are
//   fetched as 3x ds_read_b128 (1.5 LDS inst/comp). 6 VALU + 1 exp2 per term.
__global__ __launch_bounds__(1024)
void gm_all(const float* __restrict__ sample,
            const float* __restrict__ mu,
            const float* __restrict__ A,
            const float* __restrict__ w,
            float* __restrict__ out) {
    __shared__ __align__(16) float coef[M*6];     // 24 KiB, stride 6
    __shared__ float partial[16*256];             // 16 KiB
    __shared__ float red[16];

    const int t    = threadIdx.x;
    const int lane = t & 63;
    const int wv   = t >> 6;                      // 0..15
    const int base = blockIdx.x * 256;

    // ---- issue sample loads early (overlap with prep) ----
    float x0[4], x1[4];
    #pragma unroll
    for (int k = 0; k < 4; k++) {
        const float2 p = ((const float2*)sample)[base + 64*k + lane];
        x0[k] = p.x; x1[k] = p.y;
    }

    // ---- prep: component j = t ----
    const float4 a = ((const float4*)A)[t];       // A00,A01,A10,A11
    const float g00 = a.x*a.x + a.y*a.y;
    const float g01 = a.x*a.z + a.y*a.w;
    const float g11 = a.z*a.z + a.w*a.w;
    const float2 m  = ((const float2*)mu)[t];
    const float gm0 = g00*m.x + g01*m.y;
    const float gm1 = g01*m.x + g11*m.y;
    const float mGm = gm0*m.x + gm1*m.y;
    const float det = g00*g11 - g01*g01;
    const float wj  = w[t];

    // block max of w
    float r = wave_max64(wj);
    if (lane == 0) red[wv] = r;
    __syncthreads();
    float wmax = red[0];
    #pragma unroll
    for (int i = 1; i < 16; i++) wmax = fmaxf(wmax, red[i]);
    __syncthreads();

    // block sum of exp(w - wmax)
    r = wave_sum64(expf(wj - wmax));
    if (lane == 0) red[wv] = r;
    __syncthreads();
    float se = 0.0f;
    #pragma unroll
    for (int i = 0; i < 16; i++) se += red[i];
    const float lse = wmax + logf(se);
    __syncthreads();

    const float log_w = wj - lse + 0.5f * logf(det);

    // block max of log_w -> global shift L (v = log_w - q <= L since q >= 0)
    r = wave_max64(log_w);
    if (lane == 0) red[wv] = r;
    __syncthreads();
    float L = red[0];
    #pragma unroll
    for (int i = 1; i < 16; i++) L = fmaxf(L, red[i]);

    float* c = coef + t*6;
    c[0] = LOG2E * (log_w - mGm - L);
    c[1] = LOG2E * 2.0f * gm0;
    c[2] = LOG2E * 2.0f * gm1;
    c[3] = -LOG2E * g00;
    c[4] = -LOG2E * 2.0f * g01;
    c[5] = -LOG2E * g11;
    __syncthreads();

    // ---- main loop ----
    const float xx[4] = {x0[0]*x0[0], x0[1]*x0[1], x0[2]*x0[2], x0[3]*x0[3]};
    const float xy[4] = {x0[0]*x1[0], x0[1]*x1[1], x0[2]*x1[2], x0[3]*x1[3]};
    const float yy[4] = {x1[0]*x1[0], x1[1]*x1[1], x1[2]*x1[2], x1[3]*x1[3]};
    float acc[4] = {0.0f, 0.0f, 0.0f, 0.0f};

    // wave wv owns components [wv*64, wv*64+64), processed in pairs:
    // pair base byte offset = comp*24, 16B-aligned for even comp.
    const float4* cw = (const float4*)(coef + wv*64*6);
    #pragma unroll 4
    for (int jj = 0; jj < 32; jj++) {
        const float4 q0 = cw[jj*3 + 0];   // c0a c1a c2a c3a
        const float4 q1 = cw[jj*3 + 1];   // c4a c5a c0b c1b
        const float4 q2 = cw[jj*3 + 2];   // c2b c3b c4b c5b
        #pragma unroll
        for (int k = 0; k < 4; k++) {
            const float va = fmaf(q1.y, yy[k], fmaf(q1.x, xy[k],
                             fmaf(q0.w, xx[k], fmaf(q0.z, x1[k],
                             fmaf(q0.y, x0[k], q0.x)))));
            const float vb = fmaf(q2.w, yy[k], fmaf(q2.z, xy[k],
                             fmaf(q2.y, xx[k], fmaf(q2.x, x1[k],
                             fmaf(q1.w, x0[k], q1.z)))));
            acc[k] += __builtin_amdgcn_exp2f(va) + __builtin_amdgcn_exp2f(vb);
        }
    }

    #pragma unroll
    for (int k = 0; k < 4; k++)
        partial[wv*256 + 64*k + lane] = acc[k];
    __syncthreads();

    if (t < 256) {
        float s = 0.0f;
        #pragma unroll
        for (int w2 = 0; w2 < 16; w2++) s += partial[w2*256 + t];
        out[base + t] = LN2 * (LOG2E*L + __builtin_amdgcn_logf(s));
    }
}

extern "C" void kernel_launch(void* const* d_in, const int* in_sizes, int n_in,
                              void* d_out, int out_size, void* d_ws, size_t ws_size,
                              hipStream_t stream) {
    const float* sample = (const float*)d_in[0];
    const float* mu     = (const float*)d_in[1];
    const float* A      = (const float*)d_in[2];
    const float* w      = (const float*)d_in[3];
    float* out = (float*)d_out;
    (void)d_ws; (void)ws_size;

    gm_all<<<N/256, 1024, 0, stream>>>(sample, mu, A, w, out);
}

// Round 5
// 73.126 us; speedup vs baseline: 1.1226x; 1.0179x over previous
//
#include <hip/hip_runtime.h>
#include <math.h>

#define LOG2E 1.4426950408889634f
#define LN2   0.6931471805599453f

static constexpr int M = 1024;
static constexpr int N = 65536;

__device__ inline float wave_max64(float v) {
    #pragma unroll
    for (int o = 32; o > 0; o >>= 1) v = fmaxf(v, __shfl_xor(v, o));
    return v;
}
__device__ inline float wave_sum64(float v) {
    #pragma unroll
    for (int o = 32; o > 0; o >>= 1) v += __shfl_xor(v, o);
    return v;
}

// Single fused kernel: 256 blocks x 1024 threads (16 waves), 1 block/CU.
// All log-domain math in base-2 (v_exp_f32 / v_log_f32 are 2^x / log2 x).
//   t2_j  = w_j*LOG2E + 0.5*log2(det_j)
//   maxt2 = max_j t2_j                      (ONE pre-phase-2 max reduction)
//   c0_j  = t2_j - maxt2 - mGm_j*LOG2E     (lse cancels here!)
//   v2_ij = c0_j + linear/quadratic terms  (<= 0 by construction)
//   out_i = LN2 * (maxt2 - lse2 + log2 sum_j 2^{v2_ij})
//   lse2  = wmax2 + log2 sum_j 2^{w2_j - wmax2}   (only needed in epilogue)
__global__ __launch_bounds__(1024)
void gm_all(const float* __restrict__ sample,
            const float* __restrict__ mu,
            const float* __restrict__ A,
            const float* __restrict__ w,
            float* __restrict__ out) {
    __shared__ __align__(16) float coef[M*6];     // 24 KiB, stride 6
    __shared__ float partial[16*256];             // 16 KiB
    __shared__ float redA[16];
    __shared__ float redB[16];

    const int t    = threadIdx.x;
    const int lane = t & 63;
    const int wv   = t >> 6;                      // 0..15
    const int base = blockIdx.x * 256;

    // ---- sample loads issued first (overlap with prep) ----
    float x0[4], x1[4];
    #pragma unroll
    for (int k = 0; k < 4; k++) {
        const float2 p = ((const float2*)sample)[base + 64*k + lane];
        x0[k] = p.x; x1[k] = p.y;
    }

    // ---- prep: component j = t ----
    const float4 a = ((const float4*)A)[t];       // A00,A01,A10,A11
    const float g00 = a.x*a.x + a.y*a.y;
    const float g01 = a.x*a.z + a.y*a.w;
    const float g11 = a.z*a.z + a.w*a.w;
    const float2 m  = ((const float2*)mu)[t];
    const float gm0 = g00*m.x + g01*m.y;
    const float gm1 = g01*m.x + g11*m.y;
    const float mGm = gm0*m.x + gm1*m.y;
    const float det = g00*g11 - g01*g01;

    const float w2 = w[t] * LOG2E;                          // log2-domain w
    const float t2 = w2 + 0.5f * __builtin_amdgcn_logf(det); // + 0.5*log2(det)

    // joint block-max of (w2, t2): one barrier phase
    float mw = wave_max64(w2);
    float mt = wave_max64(t2);
    if (lane == 0) { redA[wv] = mw; redB[wv] = mt; }
    __syncthreads();
    float wmax2 = redA[0], maxt2 = redB[0];
    #pragma unroll
    for (int i = 1; i < 16; i++) {
        wmax2 = fmaxf(wmax2, redA[i]);
        maxt2 = fmaxf(maxt2, redB[i]);
    }

    // coefficients (phase 2 can start right after the NEXT barrier)
    {
        float* c = coef + t*6;
        c[0] = t2 - maxt2 - LOG2E * mGm;
        c[1] = LOG2E * 2.0f * gm0;
        c[2] = LOG2E * 2.0f * gm1;
        c[3] = -LOG2E * g00;
        c[4] = -LOG2E * 2.0f * g01;
        c[5] = -LOG2E * g11;
    }
    __syncthreads();

    // block-sum of 2^(w2 - wmax2) -> lse2 (needed only in epilogue)
    float sw = wave_sum64(__builtin_amdgcn_exp2f(w2 - wmax2));
    if (lane == 0) redA[wv] = sw;        // no barrier needed before phase 2:
                                         // redA re-read only after next sync

    // ---- phase 2: 16 waves split M 16-way, S=4 samples/lane ----
    const float xx[4] = {x0[0]*x0[0], x0[1]*x0[1], x0[2]*x0[2], x0[3]*x0[3]};
    const float xy[4] = {x0[0]*x1[0], x0[1]*x1[1], x0[2]*x1[2], x0[3]*x1[3]};
    const float yy[4] = {x1[0]*x1[0], x1[1]*x1[1], x1[2]*x1[2], x1[3]*x1[3]};
    float accA[4] = {0.0f, 0.0f, 0.0f, 0.0f};
    float accB[4] = {0.0f, 0.0f, 0.0f, 0.0f};

    // wave wv owns components [wv*64, wv*64+64) in pairs: 3x ds_read_b128.
    const float4* cw = (const float4*)(coef + wv*64*6);
    #pragma unroll 8
    for (int jj = 0; jj < 32; jj++) {
        const float4 q0 = cw[jj*3 + 0];   // c0a c1a c2a c3a
        const float4 q1 = cw[jj*3 + 1];   // c4a c5a c0b c1b
        const float4 q2 = cw[jj*3 + 2];   // c2b c3b c4b c5b
        #pragma unroll
        for (int k = 0; k < 4; k++) {
            const float va = fmaf(q1.y, yy[k], fmaf(q1.x, xy[k],
                             fmaf(q0.w, xx[k], fmaf(q0.z, x1[k],
                             fmaf(q0.y, x0[k], q0.x)))));
            const float vb = fmaf(q2.w, yy[k], fmaf(q2.z, xy[k],
                             fmaf(q2.y, xx[k], fmaf(q2.x, x1[k],
                             fmaf(q1.w, x0[k], q1.z)))));
            accA[k] += __builtin_amdgcn_exp2f(va);
            accB[k] += __builtin_amdgcn_exp2f(vb);
        }
    }

    #pragma unroll
    for (int k = 0; k < 4; k++)
        partial[wv*256 + 64*k + lane] = accA[k] + accB[k];
    __syncthreads();

    if (t < 256) {
        float s = 0.0f;
        #pragma unroll
        for (int w2i = 0; w2i < 16; w2i++) s += partial[w2i*256 + t];
        float se = 0.0f;
        #pragma unroll
        for (int i = 0; i < 16; i++) se += redA[i];
        const float lse2 = wmax2 + __builtin_amdgcn_logf(se);
        out[base + t] = LN2 * (maxt2 - lse2 + __builtin_amdgcn_logf(s));
    }
}

extern "C" void kernel_launch(void* const* d_in, const int* in_sizes, int n_in,
                              void* d_out, int out_size, void* d_ws, size_t ws_size,
                              hipStream_t stream) {
    const float* sample = (const float*)d_in[0];
    const float* mu     = (const float*)d_in[1];
    const float* A      = (const float*)d_in[2];
    const float* w      = (const float*)d_in[3];
    float* out = (float*)d_out;
    (void)d_ws; (void)ws_size;

    gm_all<<<N/256, 1024, 0, stream>>>(sample, mu, A, w, out);
}